// Round 3
// baseline (715.490 us; speedup 1.0000x reference)
//
#include <hip/hip_runtime.h>

typedef __attribute__((ext_vector_type(4))) float f32x4;
typedef __attribute__((ext_vector_type(8))) short bf16x8;
typedef __attribute__((ext_vector_type(4))) int i32x4;

#define MFMA __builtin_amdgcn_mfma_f32_16x16x32_bf16

union FR { i32x4 i; bf16x8 h; };

__device__ __forceinline__ unsigned short f2bf(float f) {
  unsigned int u = __float_as_uint(f);
  return (unsigned short)((u + 0x7FFFu + ((u >> 16) & 1u)) >> 16);
}
__device__ __forceinline__ unsigned int pack2(float a, float b) {
  return (unsigned int)f2bf(a) | ((unsigned int)f2bf(b) << 16);
}
// xs/at rows (512B): XOR byte bits 4..6 with ((tok>>3)^tok)&7
__device__ __forceinline__ int xsw(int tok, int cb) {
  return (tok * 512 + cb) ^ ((((tok >> 3) ^ tok) & 7) << 4);
}
// 2 shfl + select: value 'a' from acc-set0, 'b' from acc-set1, by dst half
__device__ __forceinline__ int shsel(unsigned int a, unsigned int b, int src, bool hi) {
  int va = __shfl((int)a, src, 64);
  int vb = __shfl((int)b, src, 64);
  return hi ? vb : va;
}

__global__ void convw_kernel(const float* __restrict__ wqkv,
                             const float* __restrict__ wout,
                             unsigned short* __restrict__ dst) {
  int i = blockIdx.x * 256 + threadIdx.x;
  if (i < 196608) dst[i] = f2bf(wqkv[i]);
  if (i < 65536) dst[196608 + i] = f2bf(wout[i]);
}

__global__ __launch_bounds__(256, 3) void wattn_kernel(
    const float* __restrict__ x, const unsigned short* __restrict__ wqkv,
    const unsigned short* __restrict__ wout, const float* __restrict__ bo,
    float* __restrict__ y) {
  __shared__ __align__(16) char lds[32768];   // XS, later aliased as AT

  const int tid = threadIdx.x;
  const int l = tid & 63;
  const int w = tid >> 6;      // wave 0..3
  const int lo = l & 15;
  const int dg = l >> 4;       // 0..3

  // XCD-chunked block swizzle (bijective: 4096 = 8*512)
  const int bid = blockIdx.x;
  const int rw = ((bid & 7) << 9) | (bid >> 3);
  const int b = rw >> 10;
  const int rem = rw & 1023;
  const int wy = rem >> 5;
  const int wx = rem & 31;

  const size_t wbase = ((size_t)b * 65536 + (size_t)wy * 8) * 256 + (size_t)wx * 8;
  const float* xw = x + wbase;
  float* yw = y + wbase;

  // ---- stage x window -> xs[tok][c] bf16 ----
  {
    const int irow = lo >> 1;
    const int jq = lo & 1;
    const float* xp = xw + irow * 256 + jq * 4;
    const int tok0 = irow * 8 + jq * 4;
#pragma unroll
    for (int cc = 0; cc < 4; ++cc) {
      const int cb = w * 64 + cc * 16 + dg * 4;
      f32x4 v0 = *(const f32x4*)(xp + (size_t)(cb + 0) * 65536);
      f32x4 v1 = *(const f32x4*)(xp + (size_t)(cb + 1) * 65536);
      f32x4 v2 = *(const f32x4*)(xp + (size_t)(cb + 2) * 65536);
      f32x4 v3 = *(const f32x4*)(xp + (size_t)(cb + 3) * 65536);
#pragma unroll
      for (int t = 0; t < 4; ++t) {
        uint2 uu;
        uu.x = pack2(v0[t], v1[t]);
        uu.y = pack2(v2[t], v3[t]);
        *(uint2*)(lds + xsw(tok0 + t, cb * 2)) = uu;
      }
    }
  }
  __syncthreads();   // bar 1 of 3

  const float lscale = 0.17677669529663687f * 1.4426950408889634f;

  // shuffle source-lane patterns (see derivation in journal)
  const int srcQK0 = (((2 * dg) & 3) << 4) | lo;
  const int srcQK1 = (((2 * dg + 1) & 3) << 4) | lo;
  const int srcVP0 = (((dg & 1) * 2) << 4) | lo;
  const int srcVP1 = (((dg & 1) * 2 + 1) << 4) | lo;
  const bool hi = dg >= 2;

  unsigned int outp[2][2][4][2];   // [hh][dt][it][pair] packed bf16 attn-out

#pragma unroll
  for (int hh = 0; hh < 2; ++hh) {
    const int h = w * 2 + hh;
    const unsigned short* wp = wqkv + (size_t)(h * 32 + lo) * 256 + dg * 8;

    // ---- pass 1: Q,K projection ----
    f32x4 qa[2][4], ka[2][4];
#pragma unroll
    for (int dt = 0; dt < 2; ++dt)
#pragma unroll
      for (int it = 0; it < 4; ++it) {
        qa[dt][it] = {0.f, 0.f, 0.f, 0.f};
        ka[dt][it] = {0.f, 0.f, 0.f, 0.f};
      }
#pragma unroll
    for (int kk = 0; kk < 8; ++kk) {
      bf16x8 xf[4];
#pragma unroll
      for (int it = 0; it < 4; ++it)
        xf[it] = *(const bf16x8*)(lds + xsw(it * 16 + lo, kk * 64 + dg * 16));
      bf16x8 wq0 = *(const bf16x8*)(wp + kk * 32);
      bf16x8 wq1 = *(const bf16x8*)(wp + 4096 + kk * 32);
      bf16x8 wk0 = *(const bf16x8*)(wp + 65536 + kk * 32);
      bf16x8 wk1 = *(const bf16x8*)(wp + 69632 + kk * 32);
#pragma unroll
      for (int it = 0; it < 4; ++it) {
        qa[0][it] = MFMA(wq0, xf[it], qa[0][it], 0, 0, 0);  // q[d][tok]
        qa[1][it] = MFMA(wq1, xf[it], qa[1][it], 0, 0, 0);
        ka[0][it] = MFMA(wk0, xf[it], ka[0][it], 0, 0, 0);
        ka[1][it] = MFMA(wk1, xf[it], ka[1][it], 0, 0, 0);
      }
    }
    // acc -> B/A frags via in-wave shuffles (no LDS)
    bf16x8 qf[4], kf[4];
#pragma unroll
    for (int it = 0; it < 4; ++it) {
      unsigned int a0 = pack2(qa[0][it][0], qa[0][it][1]);
      unsigned int a1 = pack2(qa[0][it][2], qa[0][it][3]);
      unsigned int b0 = pack2(qa[1][it][0], qa[1][it][1]);
      unsigned int b1 = pack2(qa[1][it][2], qa[1][it][3]);
      FR r;
      r.i[0] = shsel(a0, b0, srcQK0, hi);
      r.i[1] = shsel(a1, b1, srcQK0, hi);
      r.i[2] = shsel(a0, b0, srcQK1, hi);
      r.i[3] = shsel(a1, b1, srcQK1, hi);
      qf[it] = r.h;
      a0 = pack2(ka[0][it][0], ka[0][it][1]);
      a1 = pack2(ka[0][it][2], ka[0][it][3]);
      b0 = pack2(ka[1][it][0], ka[1][it][1]);
      b1 = pack2(ka[1][it][2], ka[1][it][3]);
      r.i[0] = shsel(a0, b0, srcQK0, hi);
      r.i[1] = shsel(a1, b1, srcQK0, hi);
      r.i[2] = shsel(a0, b0, srcQK1, hi);
      r.i[3] = shsel(a1, b1, srcQK1, hi);
      kf[it] = r.h;
    }

    // ---- pass 2: V projection ----
    f32x4 va[4][2];
#pragma unroll
    for (int it = 0; it < 4; ++it)
#pragma unroll
      for (int dt = 0; dt < 2; ++dt) va[it][dt] = {0.f, 0.f, 0.f, 0.f};
#pragma unroll
    for (int kk = 0; kk < 8; ++kk) {
      bf16x8 xf[4];
#pragma unroll
      for (int it = 0; it < 4; ++it)
        xf[it] = *(const bf16x8*)(lds + xsw(it * 16 + lo, kk * 64 + dg * 16));
      bf16x8 wv0 = *(const bf16x8*)(wp + 131072 + kk * 32);
      bf16x8 wv1 = *(const bf16x8*)(wp + 135168 + kk * 32);
#pragma unroll
      for (int it = 0; it < 4; ++it) {
        va[it][0] = MFMA(xf[it], wv0, va[it][0], 0, 0, 0);  // v^T[tok][d]
        va[it][1] = MFMA(xf[it], wv1, va[it][1], 0, 0, 0);
      }
    }
    unsigned int pv[4][2][2];
#pragma unroll
    for (int it = 0; it < 4; ++it)
#pragma unroll
      for (int dt = 0; dt < 2; ++dt) {
        pv[it][dt][0] = pack2(va[it][dt][0], va[it][dt][1]);
        pv[it][dt][1] = pack2(va[it][dt][2], va[it][dt][3]);
      }
    bf16x8 vf[2][2];
#pragma unroll
    for (int dt = 0; dt < 2; ++dt)
#pragma unroll
      for (int ks = 0; ks < 2; ++ks) {
        FR r;
        r.i[0] = shsel(pv[2 * ks][dt][0], pv[2 * ks + 1][dt][0], srcVP0, hi);
        r.i[1] = shsel(pv[2 * ks][dt][1], pv[2 * ks + 1][dt][1], srcVP0, hi);
        r.i[2] = shsel(pv[2 * ks][dt][0], pv[2 * ks + 1][dt][0], srcVP1, hi);
        r.i[3] = shsel(pv[2 * ks][dt][1], pv[2 * ks + 1][dt][1], srcVP1, hi);
        vf[dt][ks] = r.h;
      }

    // ---- S^T, softmax, PV — per i-tile (keeps st at 4 accs) ----
#pragma unroll
    for (int it = 0; it < 4; ++it) {
      f32x4 stt[4];
#pragma unroll
      for (int jt = 0; jt < 4; ++jt) {
        f32x4 z = {0.f, 0.f, 0.f, 0.f};
        stt[jt] = MFMA(kf[jt], qf[it], z, 0, 0, 0);   // S^T[j][i]
      }
      float m = stt[0][0];
#pragma unroll
      for (int jt = 0; jt < 4; ++jt)
#pragma unroll
        for (int t = 0; t < 4; ++t) m = fmaxf(m, stt[jt][t]);
      m = fmaxf(m, __shfl_xor(m, 16, 64));
      m = fmaxf(m, __shfl_xor(m, 32, 64));
      float s = 0.f;
#pragma unroll
      for (int jt = 0; jt < 4; ++jt)
#pragma unroll
        for (int t = 0; t < 4; ++t) {
          float e = exp2f((stt[jt][t] - m) * lscale);
          stt[jt][t] = e;
          s += e;
        }
      s += __shfl_xor(s, 16, 64);
      s += __shfl_xor(s, 32, 64);
      const float rs = 1.0f / s;

      unsigned int pp[4][2];
#pragma unroll
      for (int jt = 0; jt < 4; ++jt) {
        pp[jt][0] = pack2(stt[jt][0], stt[jt][1]);
        pp[jt][1] = pack2(stt[jt][2], stt[jt][3]);
      }
      bf16x8 pf[2];
#pragma unroll
      for (int ks = 0; ks < 2; ++ks) {
        FR r;
        r.i[0] = shsel(pp[2 * ks][0], pp[2 * ks + 1][0], srcVP0, hi);
        r.i[1] = shsel(pp[2 * ks][1], pp[2 * ks + 1][1], srcVP0, hi);
        r.i[2] = shsel(pp[2 * ks][0], pp[2 * ks + 1][0], srcVP1, hi);
        r.i[3] = shsel(pp[2 * ks][1], pp[2 * ks + 1][1], srcVP1, hi);
        pf[ks] = r.h;
      }
#pragma unroll
      for (int dt = 0; dt < 2; ++dt) {
        f32x4 z = {0.f, 0.f, 0.f, 0.f};
        f32x4 o = MFMA(vf[dt][0], pf[0], z, 0, 0, 0);   // out^T[d][i]
        o = MFMA(vf[dt][1], pf[1], o, 0, 0, 0);
        o *= rs;
        outp[hh][dt][it][0] = pack2(o[0], o[1]);
        outp[hh][dt][it][1] = pack2(o[2], o[3]);
      }
    }
  }

  __syncthreads();   // bar 2 of 3: all XS reads done; safe to alias as AT

#pragma unroll
  for (int hh = 0; hh < 2; ++hh) {
    const int h = w * 2 + hh;
#pragma unroll
    for (int dt = 0; dt < 2; ++dt)
#pragma unroll
      for (int it = 0; it < 4; ++it) {
        uint2 uu;
        uu.x = outp[hh][dt][it][0];
        uu.y = outp[hh][dt][it][1];
        *(uint2*)(lds + xsw(it * 16 + lo, h * 64 + dt * 32 + dg * 8)) = uu;
      }
  }
  __syncthreads();   // bar 3 of 3

  // ---- final projection: Y^T = attn @ Wout^T for o in [w*64, w*64+64) ----
  const unsigned short* wo0 = wout + (size_t)(w * 64 + lo) * 256 + dg * 8;
  f32x4 ya[4][4];
#pragma unroll
  for (int ot = 0; ot < 4; ++ot)
#pragma unroll
    for (int it = 0; it < 4; ++it) ya[ot][it] = {0.f, 0.f, 0.f, 0.f};
#pragma unroll
  for (int kk = 0; kk < 8; ++kk) {
    bf16x8 bt[4];
#pragma unroll
    for (int it = 0; it < 4; ++it)
      bt[it] = *(const bf16x8*)(lds + xsw(it * 16 + lo, kk * 64 + dg * 16));
    bf16x8 wf[4];
#pragma unroll
    for (int ot = 0; ot < 4; ++ot)
      wf[ot] = *(const bf16x8*)(wo0 + ot * 4096 + kk * 32);
#pragma unroll
    for (int ot = 0; ot < 4; ++ot)
#pragma unroll
      for (int it = 0; it < 4; ++it)
        ya[ot][it] = MFMA(bt[it], wf[ot], ya[ot][it], 0, 0, 0);
  }
#pragma unroll
  for (int ot = 0; ot < 4; ++ot) {
    const float bv = bo[w * 64 + ot * 16 + lo];
#pragma unroll
    for (int it = 0; it < 4; ++it) {
      f32x4 r = ya[ot][it];
      r[0] += bv; r[1] += bv; r[2] += bv; r[3] += bv;
      const int tok0 = it * 16 + dg * 4;
      *(f32x4*)(yw + (size_t)(w * 64 + ot * 16 + lo) * 65536 +
                (size_t)(tok0 >> 3) * 256 + (tok0 & 7)) = r;
    }
  }
}

extern "C" void kernel_launch(void* const* d_in, const int* in_sizes, int n_in,
                              void* d_out, int out_size, void* d_ws, size_t ws_size,
                              hipStream_t stream) {
  const float* x = (const float*)d_in[0];
  const float* wqkv = (const float*)d_in[1];
  const float* wout = (const float*)d_in[2];
  const float* bo = (const float*)d_in[3];
  float* y = (float*)d_out;
  unsigned short* wbf = (unsigned short*)d_ws;

  convw_kernel<<<768, 256, 0, stream>>>(wqkv, wout, wbf);
  wattn_kernel<<<4096, 256, 0, stream>>>(x, wbf, wbf + 196608, bo, y);
}